// Round 9
// baseline (296.868 us; speedup 1.0000x reference)
//
#include <hip/hip_runtime.h>
#include <cfloat>
#include <math.h>

// ---------------- output layout (flat concat, all float32) ----------------
#define O_LOSS 0
#define O_Q    1ull                         // 8388608 elements, NCHW
#define O_PERP 8388609ull
#define O_DIST 8388610ull                   // 131072 x 512
#define O_IDX  75497474ull                  // 131072
#define O_ENC  75628546ull                  // 131072 x 512

#define ETS 132   // eT LDS stride (128 + 4: 16B-aligned, 8-way-max staging banks)
#define XTS 68    // xT LDS stride (64 + 4)
#define SMEM_MAIN ((64*ETS + 64*XTS + 512 + 64) * 4)   // 53504 B -> 3 blocks/CU

// ws: [0,2048) uint hist[512]; [2048,2056) double lsum; [2064,4112) float sume2[512]

typedef float f32x2 __attribute__((ext_vector_type(2)));

// LDS-only barrier: never drains vmcnt, so global stores keep flowing
__device__ __forceinline__ void bar_lgkm() {
    asm volatile("s_waitcnt lgkmcnt(0)\n\ts_barrier" ::: "memory");
}

// ---------------- prep_e: zero accumulators, ||e_k||^2 (numpy pairwise order) ----
__global__ void vq_prep_e(const float* __restrict__ emb, unsigned int* __restrict__ hist,
                          double* __restrict__ lsum, float* __restrict__ sume2) {
    int k = threadIdx.x;   // 512 threads
    hist[k] = 0u;
    if (k == 0) *lsum = 0.0;
    float x[64];
    const float4* e4 = (const float4*)(emb + k * 64);
#pragma unroll
    for (int i = 0; i < 16; ++i) {
        float4 v = e4[i];
        x[4*i+0] = v.x; x[4*i+1] = v.y; x[4*i+2] = v.z; x[4*i+3] = v.w;
    }
    float r[8];
#pragma unroll
    for (int j = 0; j < 8; ++j) r[j] = x[j] * x[j];
#pragma unroll
    for (int i = 8; i < 64; i += 8)
#pragma unroll
        for (int j = 0; j < 8; ++j) r[j] += x[i+j] * x[i+j];
    sume2[k] = ((r[0]+r[1])+(r[2]+r[3])) + ((r[4]+r[5])+(r[6]+r[7]));
}

// ---------------- main fused kernel: 2048 blocks x 256 thr, 3 blocks/CU ----------
__global__ __launch_bounds__(256, 3)
void vq_main(const float* __restrict__ in, const float* __restrict__ emb,
             float* __restrict__ out, const float* __restrict__ sume2g,
             unsigned int* __restrict__ hist, double* __restrict__ lsum) {
    extern __shared__ float smem[];
    float*  eT  = smem;                     // [64 d][ETS] current k-quarter
    float*  xT  = smem + 64 * ETS;          // [64 c][XTS] x tile
    float2* sC  = (float2*)(xT + 64 * XTS); // [64 rows][4 waves] (dist, k)
    float*  sSX = (float*)(sC + 256);       // [64] sumx2, later kbest(float)

    const int tid  = threadIdx.x;
    const int lane = tid & 63;
    const int w    = tid >> 6;              // wave 0..3
    const int ri   = lane >> 3;             // row group: rows 8ri..8ri+7
    const int ki   = lane & 7;              // k subgroup: 4 k each
    const int row0 = blockIdx.x << 6;
    const int n    = row0 >> 12;
    const int hw0  = row0 & 4095;
    const int dq   = (tid & 15) << 2;       // staging: dword quad within 64-d row
    const int klb  = tid >> 4;              // staging: k_local / c base (0..15)

    // ---- prologue: x loads + e quarter-0 loads + per-pass sume2 (all -> regs)
    float4 xg[4];
#pragma unroll
    for (int ii = 0; ii < 4; ++ii) {
        int c = klb + 16 * ii;
        xg[ii] = *(const float4*)(in + ((size_t)(n * 64 + c) << 12) + hw0 + dq);
    }
    float4 eg[8];
#pragma unroll
    for (int it = 0; it < 8; ++it) {
        int kl = klb + 16 * it;             // k_local 0..127 of quarter 0
        eg[it] = *(const float4*)(emb + (size_t)kl * 64 + dq);
    }
    float4 seq[4];
#pragma unroll
    for (int p = 0; p < 4; ++p)
        seq[p] = *(const float4*)(sume2g + 128 * p + 32 * w + 4 * ki);

    // ---- stage xT + eT(quarter 0)
#pragma unroll
    for (int ii = 0; ii < 4; ++ii)
        *(float4*)&xT[(klb + 16 * ii) * XTS + dq] = xg[ii];
#pragma unroll
    for (int it = 0; it < 8; ++it) {
        int kl = klb + 16 * it;
        eT[(dq+0)*ETS + kl] = eg[it].x;
        eT[(dq+1)*ETS + kl] = eg[it].y;
        eT[(dq+2)*ETS + kl] = eg[it].z;
        eT[(dq+3)*ETS + kl] = eg[it].w;
    }
    bar_lgkm();

    // ---- sumx2 per row (numpy 8-accumulator pairwise order; proven exact)
    if (tid < 64) {
        float r8[8];
#pragma unroll
        for (int j = 0; j < 8; ++j) { float v = xT[j * XTS + tid]; r8[j] = v * v; }
        for (int i = 8; i < 64; i += 8)
#pragma unroll
            for (int j = 0; j < 8; ++j) { float v = xT[(i + j) * XTS + tid]; r8[j] += v * v; }
        sSX[tid] = ((r8[0]+r8[1])+(r8[2]+r8[3])) + ((r8[4]+r8[5])+(r8[6]+r8[7]));
    }

    const float* er = eT + 32 * w + 4 * ki;
    const float* xr = xT + 8 * ri;

    float sx[8];
    float bd[8]; int bk[8];
#pragma unroll
    for (int m = 0; m < 8; ++m) { bd[m] = FLT_MAX; bk[m] = 0; }

    for (int p = 0; p < 4; ++p) {
        // ---- issue next quarter's e loads FIRST (older than this pass's stores
        //      in the vm queue -> later ds_write never drains the store stream)
        if (p < 3) {
#pragma unroll
            for (int it = 0; it < 8; ++it) {
                int kl = klb + 16 * it;
                eg[it] = *(const float4*)(emb + (size_t)(128 * (p + 1) + kl) * 64 + dq);
            }
            __builtin_amdgcn_sched_barrier(0);
        }

        // ---- GEMM: 8 rows x 4 k per thread over 64 d (2 x-b128 + 1 e-b128 per d)
        f32x2 acc[4][4];   // [kk][m-pair]
#pragma unroll
        for (int kk = 0; kk < 4; ++kk)
#pragma unroll
            for (int mp = 0; mp < 4; ++mp) acc[kk][mp] = (f32x2){0.0f, 0.0f};

#pragma unroll 4
        for (int d = 0; d < 64; ++d) {
            float4 xa = *(const float4*)(xr + d * XTS);
            float4 xb = *(const float4*)(xr + d * XTS + 4);
            float4 ea = *(const float4*)(er + d * ETS);
            f32x2 xp[4] = {{xa.x, xa.y}, {xa.z, xa.w}, {xb.x, xb.y}, {xb.z, xb.w}};
            float ev4[4] = {ea.x, ea.y, ea.z, ea.w};
#pragma unroll
            for (int kk = 0; kk < 4; ++kk) {
                f32x2 e2 = {ev4[kk], ev4[kk]};
#pragma unroll
                for (int mp = 0; mp < 4; ++mp)
                    acc[kk][mp] = __builtin_elementwise_fma(xp[mp], e2, acc[kk][mp]);
            }
        }

        if (p == 0) {               // sSX written by wave 0 before its GEMM
            bar_lgkm();
            float4 sa = *(const float4*)&sSX[8 * ri];
            float4 sb = *(const float4*)&sSX[8 * ri + 4];
            sx[0]=sa.x; sx[1]=sa.y; sx[2]=sa.z; sx[3]=sa.w;
            sx[4]=sb.x; sx[5]=sb.y; sx[6]=sb.z; sx[7]=sb.w;
        }

        // ---- distances: store + running per-lane lex argmin (k ascending)
        const int kb = 128 * p + 32 * w + 4 * ki;
        const float se0 = seq[p].x, se1 = seq[p].y, se2 = seq[p].z, se3 = seq[p].w;
#pragma unroll
        for (int m = 0; m < 8; ++m) {
            const int mp = m >> 1;
            float d0, d1, d2, d3;
            if (m & 1) { d0=acc[0][mp].y; d1=acc[1][mp].y; d2=acc[2][mp].y; d3=acc[3][mp].y; }
            else       { d0=acc[0][mp].x; d1=acc[1][mp].x; d2=acc[2][mp].x; d3=acc[3][mp].x; }
            float v0 = (sx[m] + se0) - 2.0f * d0;   // fl(fl(a+b) - fl(2m)), proven
            float v1 = (sx[m] + se1) - 2.0f * d1;
            float v2 = (sx[m] + se2) - 2.0f * d2;
            float v3 = (sx[m] + se3) - 2.0f * d3;
            if (v0 < bd[m]) { bd[m] = v0; bk[m] = kb;     }
            if (v1 < bd[m]) { bd[m] = v1; bk[m] = kb + 1; }
            if (v2 < bd[m]) { bd[m] = v2; bk[m] = kb + 2; }
            if (v3 < bd[m]) { bd[m] = v3; bk[m] = kb + 3; }
            *(float4*)(out + O_DIST + (size_t)(row0 + 8 * ri + m) * 512 + kb)
                = make_float4(v0, v1, v2, v3);
        }

        // ---- restage eT with next quarter
        if (p < 3) {
            bar_lgkm();                       // all GEMM(p) eT reads done
#pragma unroll
            for (int it = 0; it < 8; ++it) {
                int kl = klb + 16 * it;
                eT[(dq+0)*ETS + kl] = eg[it].x;
                eT[(dq+1)*ETS + kl] = eg[it].y;
                eT[(dq+2)*ETS + kl] = eg[it].z;
                eT[(dq+3)*ETS + kl] = eg[it].w;
            }
            bar_lgkm();                       // quarter p+1 visible
        }
    }

    // ---- per-row argmin: ki-octet butterfly (lex), then cross-wave combine
#pragma unroll
    for (int m = 0; m < 8; ++m) {
        float bdm = bd[m]; int bkm = bk[m];
#pragma unroll
        for (int s = 1; s <= 4; s <<= 1) {
            float od = __shfl_xor(bdm, s, 64);
            int   ok = __shfl_xor(bkm, s, 64);
            if (od < bdm || (od == bdm && ok < bkm)) { bdm = od; bkm = ok; }
        }
        if (ki == 0) sC[(8 * ri + m) * 4 + w] = make_float2(bdm, (float)bkm);
    }
    bar_lgkm();

    if (tid < 64) {
        float bdm = FLT_MAX, bkf = 0.0f;     // lex-(d,k) min: partition-order independent
#pragma unroll
        for (int j = 0; j < 4; ++j) {
            float2 c2 = sC[tid * 4 + j];
            if (c2.x < bdm || (c2.x == bdm && c2.y < bkf)) { bdm = c2.x; bkf = c2.y; }
        }
        sSX[tid] = bkf;                       // reuse sumx2 slot (sx is in regs now)
        out[O_IDX + row0 + tid] = bkf;
        atomicAdd(&hist[(int)bkf], 1u);
    }
    bar_lgkm();

    // ---- emit: gather loads FIRST, then enc stores, then q + loss
    float evv[16];
#pragma unroll
    for (int i = 0; i < 16; ++i)
        evv[i] = emb[(size_t)((int)sSX[4 * i + w]) * 64 + lane];
    __builtin_amdgcn_sched_barrier(0);

#pragma unroll 4
    for (int i = 0; i < 32; ++i) {
        int f4i = tid + (i << 8);            // 0..8191
        int r   = f4i >> 7;
        int k0  = (f4i & 127) << 2;
        int kbr = (int)sSX[r];
        *(float4*)(out + O_ENC + (size_t)(row0 + r) * 512 + k0) = make_float4(
            (k0     == kbr) ? 1.0f : 0.0f, (k0 + 1 == kbr) ? 1.0f : 0.0f,
            (k0 + 2 == kbr) ? 1.0f : 0.0f, (k0 + 3 == kbr) ? 1.0f : 0.0f);
    }

    float* eL = smem;                        // reuse eT region: [64 rows][XTS]
#pragma unroll
    for (int i = 0; i < 16; ++i) eL[(4 * i + w) * XTS + lane] = evv[i];
    bar_lgkm();

    double lacc = 0.0;
#pragma unroll 4
    for (int i = 0; i < 16; ++i) {
        int c = 4 * i + w;
        float x  = xT[c * XTS + lane];
        float dd = eL[lane * XTS + c] - x;   // fl(q-x), as reference
        lacc += (double)(dd * dd);
        out[O_Q + ((size_t)(n * 64 + c) << 12) + hw0 + lane] = x + dd;  // x + (q-x)
    }

    double v = lacc;
    for (int s = 32; s >= 1; s >>= 1) v += __shfl_down(v, s, 64);
    if (lane == 0) atomicAdd(lsum, v);
}

// ---------------- final: perplexity + loss scalars ----------------
__global__ void vq_final(const unsigned int* __restrict__ hist,
                         const double* __restrict__ lsum, float* __restrict__ out) {
    __shared__ double part[8];
    int k = threadIdx.x;                    // 512 threads
    float p = (float)hist[k] / 131072.0f;   // exact (count * 2^-17)
    double v = (double)(p * logf(p + 1e-10f));
    for (int s = 32; s >= 1; s >>= 1) v += __shfl_down(v, s, 64);
    if ((k & 63) == 0) part[k >> 6] = v;
    __syncthreads();
    if (k == 0) {
        double S = 0.0;
#pragma unroll
        for (int i = 0; i < 8; ++i) S += part[i];
        out[O_PERP] = (float)exp(-S);
        float vl = (float)(*lsum / 8388608.0);
        out[O_LOSS] = vl + 0.25f * vl;      // q_latent + 0.25 * e_latent (equal values)
    }
}

// ---------------- launcher ----------------
extern "C" void kernel_launch(void* const* d_in, const int* in_sizes, int n_in,
                              void* d_out, int out_size, void* d_ws, size_t ws_size,
                              hipStream_t stream) {
    const float* in  = (const float*)d_in[0];   // (32,64,64,64) NCHW fp32
    const float* emb = (const float*)d_in[1];   // (512,64) fp32
    float* out = (float*)d_out;

    unsigned int* hist = (unsigned int*)d_ws;
    double* lsum  = (double*)((char*)d_ws + 2048);
    float*  sume2 = (float*)((char*)d_ws + 2064);

    hipFuncSetAttribute((const void*)vq_main,
                        hipFuncAttributeMaxDynamicSharedMemorySize, SMEM_MAIN);

    vq_prep_e<<<1, 512, 0, stream>>>(emb, hist, lsum, sume2);
    vq_main<<<2048, 256, SMEM_MAIN, stream>>>(in, emb, out, sume2, hist, lsum);
    vq_final<<<1, 512, 0, stream>>>(hist, lsum, out);
}

// Round 10
// 223.733 us; speedup vs baseline: 1.3269x; 1.3269x over previous
//
#include <hip/hip_runtime.h>
#include <cfloat>
#include <math.h>

// ---------------- problem constants ----------------
#define NBLOCKS 256
#define NT 8                 // tiles per block
#define ESTR 516             // padded LDS stride for eT (R2-proven)

// output layout (flat concat, all float32)
#define O_LOSS 0
#define O_Q    1ull                         // 8388608 elements, NCHW
#define O_PERP 8388609ull
#define O_DIST 8388610ull                   // 131072 x 512
#define O_IDX  75497474ull                  // 131072
#define O_ENC  75628546ull                  // 131072 x 512

// eT + xT + sumx2 + idx
#define SMEM_BYTES ((64*ESTR + 64*64 + 64 + 64) * 4)   // 148992 B

// ws layout: [0,2048) uint hist[512]; [2048,2056) double loss_sum; [2064,...) float sume2[512]

// LDS-only barrier: never drains vmcnt, so global stores keep flowing.
__device__ __forceinline__ void bar_lgkm() {
    asm volatile("s_waitcnt lgkmcnt(0)\n\ts_barrier" ::: "memory");
}

// ---------------- prep: zero accumulators, compute ||e_k||^2 (numpy pairwise order) ----
__global__ void vq_prep(const float* __restrict__ emb, unsigned int* __restrict__ hist,
                        double* __restrict__ lsum, float* __restrict__ sume2) {
    int k = threadIdx.x;   // 512 threads
    hist[k] = 0u;
    if (k == 0) *lsum = 0.0;
    float x[64];
    const float4* e4 = (const float4*)(emb + k * 64);
#pragma unroll
    for (int i = 0; i < 16; ++i) {
        float4 v = e4[i];
        x[4*i+0] = v.x; x[4*i+1] = v.y; x[4*i+2] = v.z; x[4*i+3] = v.w;
    }
    float r[8];
#pragma unroll
    for (int j = 0; j < 8; ++j) r[j] = x[j] * x[j];
#pragma unroll
    for (int i = 8; i < 64; i += 8)
#pragma unroll
        for (int j = 0; j < 8; ++j) r[j] += x[i+j] * x[i+j];
    sume2[k] = ((r[0]+r[1])+(r[2]+r[3])) + ((r[4]+r[5])+(r[6]+r[7]));
}

// ---------------- main kernel (R2 skeleton + preload-all + enc interleave) -------
__global__ __launch_bounds__(512, 2)
void vq_main(const float* __restrict__ in, const float* __restrict__ emb,
             float* __restrict__ out, unsigned int* __restrict__ hist,
             double* __restrict__ lsum, const float* __restrict__ sume2g) {
    extern __shared__ float smem[];
    float* eT      = smem;                  // [64][ESTR]
    float* xT      = eT + 64 * ESTR;        // [64][64]
    float* s_sumx2 = xT + 64 * 64;          // [64]
    int*   s_idx   = (int*)(s_sumx2 + 64);  // [64]  (holds kbest of the CURRENT argmin'd tile)

    const int tid  = threadIdx.x;
    const int lane = tid & 63;              // k-thread: k = 256*j + 4*lane + q
    const int w    = tid >> 6;              // wave 0..7: rows 8w..8w+7

    // ---- prologue: issue ALL global loads (none remain in the main loop) ----
    float4 ev16[16];
    {
        const float4* e4 = (const float4*)emb;
#pragma unroll
        for (int it = 0; it < 16; ++it) ev16[it] = e4[tid + 512 * it];
    }
    const int browbase = blockIdx.x * NT * 64;
    float4 pf[NT][2];
#pragma unroll
    for (int t = 0; t < NT; ++t) {
        const int row0 = browbase + (t << 6);
        const int n    = row0 >> 12;
        const int hw0  = row0 & 4095;
        const float* inbase = in + (size_t)(n * 64) * 4096 + hw0;
#pragma unroll
        for (int it = 0; it < 2; ++it) {
            int idx4 = tid + 512 * it;      // 0..1023 float4s
            int c = idx4 >> 4, qd = (idx4 & 15) << 2;
            pf[t][it] = *(const float4*)(inbase + (size_t)c * 4096 + qd);
        }
    }
    float4 se0 = *(const float4*)(sume2g + 4 * lane);
    float4 se1 = *(const float4*)(sume2g + 256 + 4 * lane);
    const float se[8] = {se0.x, se0.y, se0.z, se0.w, se1.x, se1.y, se1.z, se1.w};

    // ---- stage codebook transposed: eT[d][k] = emb[k*64+d]  (R2 verbatim)
#pragma unroll 4
    for (int it = 0; it < 16; ++it) {
        int idx4 = tid + 512 * it;
        int k  = idx4 >> 4;
        int dq = (idx4 & 15) << 2;
        float4 v = ev16[it];
        eT[(dq+0)*ESTR + k] = v.x;
        eT[(dq+1)*ESTR + k] = v.y;
        eT[(dq+2)*ESTR + k] = v.z;
        eT[(dq+3)*ESTR + k] = v.w;
    }
    // ---- commit tile 0
#pragma unroll
    for (int it = 0; it < 2; ++it) {
        int idx4 = tid + 512 * it;
        int c = idx4 >> 4, qd = (idx4 & 15) << 2;
        *(float4*)&xT[c * 64 + qd] = pf[0][it];
    }
    bar_lgkm();

    double lacc = 0.0;

#pragma unroll 1
    for (int t = 0; t < NT; ++t) {
        const int row0 = browbase + (t << 6);
        const int n    = row0 >> 12;
        const int hw0  = row0 & 4095;

        // ---- sum(x^2) per row, numpy pairwise order (wave 0; R2 verbatim)
        if (tid < 64) {
            float r8[8];
#pragma unroll
            for (int j = 0; j < 8; ++j) { float v = xT[j*64 + tid]; r8[j] = v * v; }
            for (int i = 8; i < 64; i += 8)
#pragma unroll
                for (int j = 0; j < 8; ++j) { float v = xT[(i+j)*64 + tid]; r8[j] += v * v; }
            s_sumx2[tid] = ((r8[0]+r8[1])+(r8[2]+r8[3])) + ((r8[4]+r8[5])+(r8[6]+r8[7]));
        }

        // ---- GEMM (8 rows x 8 k per thread) with enc(t-1) stores interleaved:
        //      one 1KB enc store per 4 d-iterations. s_idx still holds tile t-1's
        //      kbest here (it is rewritten only after bar#1 below).
        float accf[8][8];
#pragma unroll
        for (int m = 0; m < 8; ++m)
#pragma unroll
            for (int kk = 0; kk < 8; ++kk) accf[m][kk] = 0.0f;

#pragma unroll 1
        for (int dd = 0; dd < 16; ++dd) {
#pragma unroll
            for (int du = 0; du < 4; ++du) {
                const int d = 4 * dd + du;
                float4 x0 = *(const float4*)&xT[d * 64 + 8 * w];       // wave-uniform bcast
                float4 x1 = *(const float4*)&xT[d * 64 + 8 * w + 4];
                float4 e0 = *(const float4*)&eT[d * ESTR + 4 * lane];  // contiguous 1KB
                float4 e1 = *(const float4*)&eT[d * ESTR + 256 + 4 * lane];
                float xv[8] = {x0.x, x0.y, x0.z, x0.w, x1.x, x1.y, x1.z, x1.w};
                float ev[8] = {e0.x, e0.y, e0.z, e0.w, e1.x, e1.y, e1.z, e1.w};
#pragma unroll
                for (int m = 0; m < 8; ++m)
#pragma unroll
                    for (int kk = 0; kk < 8; ++kk)
                        accf[m][kk] = fmaf(xv[m], ev[kk], accf[m][kk]);
            }
            if (t > 0) {                     // uniform branch
                const int m    = dd >> 1;
                const int half = dd & 1;
                const int kbr  = s_idx[8 * w + m];          // tile t-1 kbest (LDS)
                const int k0   = (half << 8) + 4 * lane;
                const int rowP = row0 - 64 + 8 * w + m;
                *(float4*)(out + O_ENC + (size_t)rowP * 512 + k0) = make_float4(
                    (k0     == kbr) ? 1.0f : 0.0f, (k0 + 1 == kbr) ? 1.0f : 0.0f,
                    (k0 + 2 == kbr) ? 1.0f : 0.0f, (k0 + 3 == kbr) ? 1.0f : 0.0f);
            }
        }
        bar_lgkm();                          // s_sumx2 ready; enc(t-1) reads done

        // ---- distances, in-wave lex argmin, dist stores (R2 verbatim)
        float4 sxa = *(const float4*)&s_sumx2[8 * w];
        float4 sxb = *(const float4*)&s_sumx2[8 * w + 4];
        float sx[8] = {sxa.x, sxa.y, sxa.z, sxa.w, sxb.x, sxb.y, sxb.z, sxb.w};

        int bkk[8];
#pragma unroll
        for (int m = 0; m < 8; ++m) {
            const int row = row0 + 8 * w + m;
            float* dout = out + O_DIST + (size_t)row * 512;
            float bd = FLT_MAX; int bki = 0;
#pragma unroll
            for (int j = 0; j < 2; ++j) {
                float dv[4];
#pragma unroll
                for (int q = 0; q < 4; ++q) {
                    int k = 256 * j + 4 * lane + q;
                    float ts = sx[m] + se[4*j+q];             // fl(a+b) (np broadcast add)
                    float dist = ts - 2.0f * accf[m][4*j+q];  // fl(t - 2m)
                    dv[q] = dist;
                    if (dist < bd) { bd = dist; bki = k; }    // k ascending tie-break
                }
                *(float4*)&dout[256 * j + 4 * lane] = make_float4(dv[0], dv[1], dv[2], dv[3]);
            }
#pragma unroll
            for (int s = 1; s <= 32; s <<= 1) {               // lex butterfly
                float od = __shfl_xor(bd, s, 64);
                int   ok = __shfl_xor(bki, s, 64);
                if (od < bd || (od == bd && ok < bki)) { bd = od; bki = ok; }
            }
            bkk[m] = bki;
        }

        // idx + s_idx(t) + hist  (s_idx overwrite is AFTER bar#1 -> enc reads safe)
        if (lane == 0) {
#pragma unroll
            for (int m = 0; m < 8; ++m) {
                const int row = row0 + 8 * w + m;
                out[O_IDX + row] = (float)bkk[m];
                s_idx[8 * w + m] = bkk[m];
                atomicAdd(&hist[bkk[m]], 1u);
            }
        }
        bar_lgkm();                          // s_idx(t) ready

        // ---- quantized (straight-through, NCHW) + loss partial (R2 verbatim)
#pragma unroll 2
        for (int it = 0; it < 8; ++it) {
            int idx = tid + 512 * it;       // 0..4095
            int c = idx >> 6, r = idx & 63;
            float x = xT[c * 64 + r];
            float q = eT[c * ESTR + s_idx[r]];
            float dlt = q - x;              // fl(q-x), as reference
            lacc += (double)(dlt * dlt);
            out[O_Q + (size_t)(n * 64 + c) * 4096 + hw0 + r] = x + dlt;  // x + (q-x)
        }

        // ---- commit next tile (registers -> LDS; lgkm only)
        if (t + 1 < NT) {
            bar_lgkm();                      // all xT(t) readers done
#pragma unroll
            for (int it = 0; it < 2; ++it) {
                int idx4 = tid + 512 * it;
                int c = idx4 >> 4, qd = (idx4 & 15) << 2;
                *(float4*)&xT[c * 64 + qd] = pf[t + 1][it];
            }
            bar_lgkm();                      // xT(t+1) visible
        }
    }

    // ---- epilogue: enc for the last tile (s_idx holds tile 7 kbest)
    {
        const int row0 = browbase + ((NT - 1) << 6);
#pragma unroll
        for (int m = 0; m < 8; ++m) {
            const int kbr = s_idx[8 * w + m];
            const int row = row0 + 8 * w + m;
#pragma unroll
            for (int half = 0; half < 2; ++half) {
                const int k0 = (half << 8) + 4 * lane;
                *(float4*)(out + O_ENC + (size_t)row * 512 + k0) = make_float4(
                    (k0     == kbr) ? 1.0f : 0.0f, (k0 + 1 == kbr) ? 1.0f : 0.0f,
                    (k0 + 2 == kbr) ? 1.0f : 0.0f, (k0 + 3 == kbr) ? 1.0f : 0.0f);
            }
        }
    }

    // ---- loss reduction: wave reduce then one atomic per wave
    double v = lacc;
    for (int s = 32; s >= 1; s >>= 1) v += __shfl_down(v, s, 64);
    if (lane == 0) atomicAdd(lsum, v);
}

// ---------------- final: perplexity + loss scalars ----------------
__global__ void vq_final(const unsigned int* __restrict__ hist,
                         const double* __restrict__ lsum, float* __restrict__ out) {
    __shared__ double part[8];
    int k = threadIdx.x;                    // 512 threads
    float p = (float)hist[k] / 131072.0f;   // exact (count * 2^-17)
    double v = (double)(p * logf(p + 1e-10f));
    for (int s = 32; s >= 1; s >>= 1) v += __shfl_down(v, s, 64);
    if ((k & 63) == 0) part[k >> 6] = v;
    __syncthreads();
    if (k == 0) {
        double S = 0.0;
#pragma unroll
        for (int i = 0; i < 8; ++i) S += part[i];
        out[O_PERP] = (float)exp(-S);
        float vl = (float)(*lsum / 8388608.0);
        out[O_LOSS] = vl + 0.25f * vl;      // q_latent + 0.25 * e_latent (equal values)
    }
}

// ---------------- launcher ----------------
extern "C" void kernel_launch(void* const* d_in, const int* in_sizes, int n_in,
                              void* d_out, int out_size, void* d_ws, size_t ws_size,
                              hipStream_t stream) {
    const float* in  = (const float*)d_in[0];   // (32,64,64,64) NCHW fp32
    const float* emb = (const float*)d_in[1];   // (512,64) fp32
    float* out = (float*)d_out;

    unsigned int* hist = (unsigned int*)d_ws;                    // 512 * 4 B
    double* lsum = (double*)((char*)d_ws + 2048);                // 8 B
    float* sume2 = (float*)((char*)d_ws + 2064);                 // 512 * 4 B

    hipFuncSetAttribute((const void*)vq_main,
                        hipFuncAttributeMaxDynamicSharedMemorySize, SMEM_BYTES);

    vq_prep<<<1, 512, 0, stream>>>(emb, hist, lsum, sume2);
    vq_main<<<NBLOCKS, 512, SMEM_BYTES, stream>>>(in, emb, out, hist, lsum, sume2);
    vq_final<<<1, 512, 0, stream>>>(hist, lsum, out);
}